// Round 9
// baseline (164.469 us; speedup 1.0000x reference)
//
#include <hip/hip_runtime.h>
#include <hip/hip_bf16.h>

// ODEFunc: out[i] = x_N(x_i) + sum_j A[i,j] * ( edgeMLP(x_i, x_j) + wA0*x_i + wA1*x_j )
//
// R21 = byte-diet + L2-residency attack (the one lever never pulled):
//   R20's by-construction depth-8 SSA register pipeline nulled at 43us =
//   R17 (DMA ring) = R18 (contiguous). Cap is not depth/occupancy/issue/
//   address-phase. Key counter: FETCH_SIZE = 33MB invariant: A is 64MB ->
//   ~50% already L2-hit across dispatches (64MB/8 XCD = 8MB vs 4MB L2 = the
//   capacity ratio). Supply = fixed 50/50 L2/miss mix at ~1.5TB/s consumed.
//   * Pre-kernel converts A fp32 -> f16 into d_ws (RTE, PERMUTED so the main
//     kernel's proven j<->lane mapping is unchanged). 96MB copy-shaped
//     ~15-20us, stream-ordered before main (no sync needed).
//   * Main kernel = R20 verbatim except A-loads are f16: bytes/request halve
//     (16 loads/row of 512B unique), and A_f16 = 32MB = 4MB/XCD = exactly
//     L2 capacity -> near-100% L2 hit after warmup, FETCH collapses.
//   * Each 16B f16 load = 2 R20 macros; unpack via 8x v_cvt_f32_f16/step;
//     body/epilogue/numerics verbatim R20 (pp stays f32; only A quantized:
//     est +5-9e-4 on absmax 7.8e-3, threshold 4.5e-2).
//   * ws_size < 32MB fallback: R20 f32 kernel verbatim (host-side branch).
//
// MFMA layout (32x32x16, validated R2-R11):
//   A[m][k]: m = lane&31, k = (lane>>5)*8 + e
//   B[k][n]: n = lane&31, k = (lane>>5)*8 + e
//   D[m][n]: n = lane&31, m = (reg&3) + 8*(reg>>2) + 4*(lane>>5)
// Only m<16 carries WA1; D regs 8..15 ignored. C = 0 (bA1 applied in epilogue).
// In-lane epilogue: A_ij distributes into the WA2 dot; skip term in half 0 only.

#define NN 4096

typedef __fp16 half8  __attribute__((ext_vector_type(8)));
typedef __fp16 half2v __attribute__((ext_vector_type(2)));
typedef __attribute__((ext_vector_type(4)))  float f32x4;
typedef __attribute__((ext_vector_type(16))) float f32x16;

__device__ __forceinline__ half2v cvt2(float lo, float hi) {
    return __builtin_amdgcn_cvt_pkrtz(lo, hi);
}

// ---- A fp32 -> f16 convert, PERMUTED for the main kernel's lane mapping:
// B16[row*4096 + P*256 + n*8 + e] = A[row][P*256 + 4n + e]        (e<4)
//                                 = A[row][P*256 + 128 + 4n + e-4] (e>=4)
// so load-step P, lane n&31 reads its two macros' float4-equivalents as 8 f16.
__global__ __launch_bounds__(256, 8) void conv_kernel(
    const float* __restrict__ A, __fp16* __restrict__ B)
{
    const int nitems = NN * NN / 8;          // one item = 8 f16 out
    const int stride = gridDim.x * blockDim.x;
    for (int i = blockIdx.x * blockDim.x + threadIdx.x; i < nitems; i += stride) {
        const int row = i >> 9;
        const int rem = i & 511;
        const int P = rem >> 5;
        const int n = rem & 31;
        const float* s = A + (size_t)row * NN + P * 256 + n * 4;
        f32x4 lo = *(const f32x4*)s;
        f32x4 hi = *(const f32x4*)(s + 128);
        half8 h;
        h[0] = (__fp16)lo[0]; h[1] = (__fp16)lo[1];
        h[2] = (__fp16)lo[2]; h[3] = (__fp16)lo[3];
        h[4] = (__fp16)hi[0]; h[5] = (__fp16)hi[1];
        h[6] = (__fp16)hi[2]; h[7] = (__fp16)hi[3];
        *(half8*)(B + (size_t)i * 8) = h;
    }
}

// =====================  f16-A main kernel (R20 structure)  ==================
__global__ __launch_bounds__(256, 4) void odef_f16(
    const __fp16* __restrict__ A16, const float* __restrict__ x,
    const float* __restrict__ WA0, const float* __restrict__ bA0,
    const float* __restrict__ WA1, const float* __restrict__ bA1,
    const float* __restrict__ WA2, const float* __restrict__ bA2,
    const float* __restrict__ Wm0, const float* __restrict__ bm0,
    const float* __restrict__ Wm1, const float* __restrict__ bm1,
    const float* __restrict__ wA,  const float* __restrict__ wf,
    float* __restrict__ out)
{
    __shared__ float xs[NN];         // full x vector, 16KB

    const int tid  = threadIdx.x;
    const int wave = tid >> 6;
    const int lane = tid & 63;
    const int n    = lane & 31;
    const int half = lane >> 5;
    const int row  = blockIdx.x * 4 + wave;   // 1 full row per wave

    {
        const f32x4* xsrc = (const f32x4*)x;
        f32x4* xdst = (f32x4*)xs;
        #pragma unroll
        for (int i = 0; i < 4; ++i)
            xdst[tid + 256 * i] = xsrc[tid + 256 * i];
    }
    const float xi = x[row];

    union { half2v h2[4]; half8 h8; } au;
    #pragma unroll
    for (int p = 0; p < 4; ++p) {
        float lo = 0.f, hi = 0.f;
        if (n < 16) {
            int k = half * 8 + p * 2;
            lo = WA1[n * 16 + k];
            hi = WA1[n * 16 + k + 1];
        }
        au.h2[p] = cvt2(lo, hi);
    }

    half2v u2h[4], w2h[4];
    #pragma unroll
    for (int p = 0; p < 4; ++p) {
        int k0 = half * 8 + p * 2;
        u2h[p] = cvt2(fmaf(WA0[2 * k0],     xi, bA0[k0]),
                      fmaf(WA0[2 * k0 + 2], xi, bA0[k0 + 1]));
        w2h[p] = cvt2(WA0[2 * k0 + 1], WA0[2 * k0 + 3]);
    }

    half2v wa2h[4], bb[4];
    #pragma unroll
    for (int p = 0; p < 4; ++p) {
        int r  = 2 * p;
        int m0 = (r & 3) + 8 * (r >> 2) + 4 * half;
        wa2h[p] = cvt2(WA2[m0], WA2[m0 + 1]);
        bb[p]   = cvt2(bA1[m0], bA1[m0 + 1]);
    }

    const float wA1h = half ? 0.f : wA[1];
    const float c0h  = half ? 0.f : (bA2[0] + wA[0] * xi);
    const half2v z2 = { (__fp16)0.f, (__fp16)0.f };
    const f32x16 zc = {};

    float acc0 = 0.f, acc1 = 0.f;

    auto body = [&](const f32x4 xv, const f32x4 av) {
        #pragma unroll
        for (int q = 0; q < 4; q += 2) {
            half2v xg0 = cvt2(xv[q], xv[q]);
            union { half2v h2[4]; half8 h8; } b0;
            #pragma unroll
            for (int p = 0; p < 4; ++p)
                b0.h2[p] = __builtin_elementwise_max(w2h[p] * xg0 + u2h[p], z2);
            f32x16 d0 = __builtin_amdgcn_mfma_f32_32x32x16_f16(au.h8, b0.h8, zc, 0, 0, 0);

            half2v xg1 = cvt2(xv[q + 1], xv[q + 1]);
            union { half2v h2[4]; half8 h8; } b1;
            #pragma unroll
            for (int p = 0; p < 4; ++p)
                b1.h2[p] = __builtin_elementwise_max(w2h[p] * xg1 + u2h[p], z2);
            f32x16 d1 = __builtin_amdgcn_mfma_f32_32x32x16_f16(au.h8, b1.h8, zc, 0, 0, 0);

            {
                float pp = fmaf(wA1h, xv[q], c0h);
                #pragma unroll
                for (int p = 0; p < 4; ++p) {
                    half2v t = __builtin_elementwise_max(
                        cvt2(d0[2 * p], d0[2 * p + 1]) + bb[p], z2);
                    pp = __builtin_amdgcn_fdot2(t, wa2h[p], pp, false);
                }
                acc0 = fmaf(av[q], pp, acc0);
            }
            {
                float pp = fmaf(wA1h, xv[q + 1], c0h);
                #pragma unroll
                for (int p = 0; p < 4; ++p) {
                    half2v t = __builtin_elementwise_max(
                        cvt2(d1[2 * p], d1[2 * p + 1]) + bb[p], z2);
                    pp = __builtin_amdgcn_fdot2(t, wa2h[p], pp, false);
                }
                acc1 = fmaf(av[q + 1], pp, acc1);
            }
        }
    };

    __syncthreads();                 // xs ready

    // step t (0..15): 16B f16 load covers macros 2t,2t+1 (j = macro*128+4n+q)
    const __fp16* ap = A16 + (size_t)row * NN + 8 * n;
    const f32x4* xls = (const f32x4*)xs;

#define LOADA(dst, p) \
    asm volatile("global_load_dwordx4 %0, %1, off" : "=v"(dst) : "v"(p))
#define WAITV(N) do {                                              \
    asm volatile("s_waitcnt vmcnt(" #N ")" ::: "memory");          \
    __builtin_amdgcn_sched_barrier(0); } while (0)

    __builtin_amdgcn_sched_barrier(0);
    asm volatile("s_waitcnt vmcnt(0)" ::: "memory");
    __builtin_amdgcn_sched_barrier(0);

    // 16 single-assignment slots, <=8 live (R20 SSA discipline, no phis)
    half8 L0, L1, L2,  L3,  L4,  L5,  L6,  L7,
          L8, L9, L10, L11, L12, L13, L14, L15;

    LOADA(L0, ap + 256 * 0);  LOADA(L1, ap + 256 * 1);
    LOADA(L2, ap + 256 * 2);  LOADA(L3, ap + 256 * 3);
    LOADA(L4, ap + 256 * 4);  LOADA(L5, ap + 256 * 5);
    LOADA(L6, ap + 256 * 6);  LOADA(L7, ap + 256 * 7);

    // steps 0..7: wait-for-oldest vmcnt(7), consume Lt (2 macros), issue t+8
#define STEPM(T, CUR, NXT) {                                       \
        f32x4 xa = xls[n + 64 * (T)];                              \
        f32x4 xb = xls[n + 64 * (T) + 32];                         \
        WAITV(7);                                                  \
        f32x4 avA = { (float)CUR[0], (float)CUR[1],                \
                      (float)CUR[2], (float)CUR[3] };              \
        f32x4 avB = { (float)CUR[4], (float)CUR[5],                \
                      (float)CUR[6], (float)CUR[7] };              \
        body(xa, avA);                                             \
        body(xb, avB);                                             \
        LOADA(NXT, ap + 256 * ((T) + 8)); }

    STEPM(0, L0, L8)  STEPM(1, L1, L9)  STEPM(2, L2, L10) STEPM(3, L3, L11)
    STEPM(4, L4, L12) STEPM(5, L5, L13) STEPM(6, L6, L14) STEPM(7, L7, L15)

    // tail steps 8..15: descending counts, no new issues
#define STEPT(T, WN, CUR) {                                        \
        f32x4 xa = xls[n + 64 * (T)];                              \
        f32x4 xb = xls[n + 64 * (T) + 32];                         \
        WAITV(WN);                                                 \
        f32x4 avA = { (float)CUR[0], (float)CUR[1],                \
                      (float)CUR[2], (float)CUR[3] };              \
        f32x4 avB = { (float)CUR[4], (float)CUR[5],                \
                      (float)CUR[6], (float)CUR[7] };              \
        body(xa, avA);                                             \
        body(xb, avB); }

    STEPT(8,  7, L8)  STEPT(9,  6, L9)  STEPT(10, 5, L10) STEPT(11, 4, L11)
    STEPT(12, 3, L12) STEPT(13, 2, L13) STEPT(14, 1, L14) STEPT(15, 0, L15)

#undef STEPM
#undef STEPT
#undef LOADA
#undef WAITV

    float acc = acc0 + acc1;
    #pragma unroll
    for (int off = 32; off > 0; off >>= 1)
        acc += __shfl_xor(acc, off);

    if (lane == 0) {
        float xn = fmaf(wf[0], xi, bm1[0]);
        #pragma unroll
        for (int h = 0; h < 16; ++h)
            xn = fmaf(Wm1[h], fmaxf(fmaf(Wm0[h], xi, bm0[h]), 0.f), xn);
        out[row] = xn + acc;
    }
}

// =====================  f32 fallback (R20 verbatim)  ========================
__global__ __launch_bounds__(256, 4) void odef_f32(
    const float* __restrict__ x,  const float* __restrict__ A,
    const float* __restrict__ WA0, const float* __restrict__ bA0,
    const float* __restrict__ WA1, const float* __restrict__ bA1,
    const float* __restrict__ WA2, const float* __restrict__ bA2,
    const float* __restrict__ Wm0, const float* __restrict__ bm0,
    const float* __restrict__ Wm1, const float* __restrict__ bm1,
    const float* __restrict__ wA,  const float* __restrict__ wf,
    float* __restrict__ out)
{
    __shared__ float xs[NN];

    const int tid  = threadIdx.x;
    const int wave = tid >> 6;
    const int lane = tid & 63;
    const int n    = lane & 31;
    const int half = lane >> 5;
    const int row  = blockIdx.x * 4 + wave;

    {
        const f32x4* xsrc = (const f32x4*)x;
        f32x4* xdst = (f32x4*)xs;
        #pragma unroll
        for (int i = 0; i < 4; ++i)
            xdst[tid + 256 * i] = xsrc[tid + 256 * i];
    }
    const float xi = x[row];

    union { half2v h2[4]; half8 h8; } au;
    #pragma unroll
    for (int p = 0; p < 4; ++p) {
        float lo = 0.f, hi = 0.f;
        if (n < 16) {
            int k = half * 8 + p * 2;
            lo = WA1[n * 16 + k];
            hi = WA1[n * 16 + k + 1];
        }
        au.h2[p] = cvt2(lo, hi);
    }

    half2v u2h[4], w2h[4];
    #pragma unroll
    for (int p = 0; p < 4; ++p) {
        int k0 = half * 8 + p * 2;
        u2h[p] = cvt2(fmaf(WA0[2 * k0],     xi, bA0[k0]),
                      fmaf(WA0[2 * k0 + 2], xi, bA0[k0 + 1]));
        w2h[p] = cvt2(WA0[2 * k0 + 1], WA0[2 * k0 + 3]);
    }

    half2v wa2h[4], bb[4];
    #pragma unroll
    for (int p = 0; p < 4; ++p) {
        int r  = 2 * p;
        int m0 = (r & 3) + 8 * (r >> 2) + 4 * half;
        wa2h[p] = cvt2(WA2[m0], WA2[m0 + 1]);
        bb[p]   = cvt2(bA1[m0], bA1[m0 + 1]);
    }

    const float wA1h = half ? 0.f : wA[1];
    const float c0h  = half ? 0.f : (bA2[0] + wA[0] * xi);
    const half2v z2 = { (__fp16)0.f, (__fp16)0.f };
    const f32x16 zc = {};

    float acc0 = 0.f, acc1 = 0.f;

    auto body = [&](const f32x4 xv, const f32x4 av) {
        #pragma unroll
        for (int q = 0; q < 4; q += 2) {
            half2v xg0 = cvt2(xv[q], xv[q]);
            union { half2v h2[4]; half8 h8; } b0;
            #pragma unroll
            for (int p = 0; p < 4; ++p)
                b0.h2[p] = __builtin_elementwise_max(w2h[p] * xg0 + u2h[p], z2);
            f32x16 d0 = __builtin_amdgcn_mfma_f32_32x32x16_f16(au.h8, b0.h8, zc, 0, 0, 0);

            half2v xg1 = cvt2(xv[q + 1], xv[q + 1]);
            union { half2v h2[4]; half8 h8; } b1;
            #pragma unroll
            for (int p = 0; p < 4; ++p)
                b1.h2[p] = __builtin_elementwise_max(w2h[p] * xg1 + u2h[p], z2);
            f32x16 d1 = __builtin_amdgcn_mfma_f32_32x32x16_f16(au.h8, b1.h8, zc, 0, 0, 0);

            {
                float pp = fmaf(wA1h, xv[q], c0h);
                #pragma unroll
                for (int p = 0; p < 4; ++p) {
                    half2v t = __builtin_elementwise_max(
                        cvt2(d0[2 * p], d0[2 * p + 1]) + bb[p], z2);
                    pp = __builtin_amdgcn_fdot2(t, wa2h[p], pp, false);
                }
                acc0 = fmaf(av[q], pp, acc0);
            }
            {
                float pp = fmaf(wA1h, xv[q + 1], c0h);
                #pragma unroll
                for (int p = 0; p < 4; ++p) {
                    half2v t = __builtin_elementwise_max(
                        cvt2(d1[2 * p], d1[2 * p + 1]) + bb[p], z2);
                    pp = __builtin_amdgcn_fdot2(t, wa2h[p], pp, false);
                }
                acc1 = fmaf(av[q + 1], pp, acc1);
            }
        }
    };

    __syncthreads();

    const float* ap = A + (size_t)row * NN + 4 * n;
    const f32x4* xls = (const f32x4*)xs;

#define LOADA(dst, p) \
    asm volatile("global_load_dwordx4 %0, %1, off" : "=v"(dst) : "v"(p))
#define WAITV(N) do {                                              \
    asm volatile("s_waitcnt vmcnt(" #N ")" ::: "memory");          \
    __builtin_amdgcn_sched_barrier(0); } while (0)

    __builtin_amdgcn_sched_barrier(0);
    asm volatile("s_waitcnt vmcnt(0)" ::: "memory");
    __builtin_amdgcn_sched_barrier(0);

    f32x4 L0,  L1,  L2,  L3,  L4,  L5,  L6,  L7,
          L8,  L9,  L10, L11, L12, L13, L14, L15,
          L16, L17, L18, L19, L20, L21, L22, L23,
          L24, L25, L26, L27, L28, L29, L30, L31;

    LOADA(L0, ap + 128 * 0);  LOADA(L1, ap + 128 * 1);
    LOADA(L2, ap + 128 * 2);  LOADA(L3, ap + 128 * 3);
    LOADA(L4, ap + 128 * 4);  LOADA(L5, ap + 128 * 5);
    LOADA(L6, ap + 128 * 6);  LOADA(L7, ap + 128 * 7);

#define STEPM(T, CUR, NXT) {                                       \
        f32x4 xv = xls[n + 32 * (T)];                              \
        WAITV(7);                                                  \
        body(xv, CUR);                                             \
        LOADA(NXT, ap + 128 * ((T) + 8)); }

    STEPM(0,  L0,  L8)   STEPM(1,  L1,  L9)   STEPM(2,  L2,  L10)
    STEPM(3,  L3,  L11)  STEPM(4,  L4,  L12)  STEPM(5,  L5,  L13)
    STEPM(6,  L6,  L14)  STEPM(7,  L7,  L15)  STEPM(8,  L8,  L16)
    STEPM(9,  L9,  L17)  STEPM(10, L10, L18)  STEPM(11, L11, L19)
    STEPM(12, L12, L20)  STEPM(13, L13, L21)  STEPM(14, L14, L22)
    STEPM(15, L15, L23)  STEPM(16, L16, L24)  STEPM(17, L17, L25)
    STEPM(18, L18, L26)  STEPM(19, L19, L27)  STEPM(20, L20, L28)
    STEPM(21, L21, L29)  STEPM(22, L22, L30)  STEPM(23, L23, L31)

#define STEPT(T, WN, CUR) {                                        \
        f32x4 xv = xls[n + 32 * (T)];                              \
        WAITV(WN);                                                 \
        body(xv, CUR); }

    STEPT(24, 7, L24) STEPT(25, 6, L25) STEPT(26, 5, L26) STEPT(27, 4, L27)
    STEPT(28, 3, L28) STEPT(29, 2, L29) STEPT(30, 1, L30) STEPT(31, 0, L31)

#undef STEPM
#undef STEPT
#undef LOADA
#undef WAITV

    float acc = acc0 + acc1;
    #pragma unroll
    for (int off = 32; off > 0; off >>= 1)
        acc += __shfl_xor(acc, off);

    if (lane == 0) {
        float xn = fmaf(wf[0], xi, bm1[0]);
        #pragma unroll
        for (int h = 0; h < 16; ++h)
            xn = fmaf(Wm1[h], fmaxf(fmaf(Wm0[h], xi, bm0[h]), 0.f), xn);
        out[row] = xn + acc;
    }
}

extern "C" void kernel_launch(void* const* d_in, const int* in_sizes, int n_in,
                              void* d_out, int out_size, void* d_ws, size_t ws_size,
                              hipStream_t stream) {
    const float* x   = (const float*)d_in[1];
    const float* A   = (const float*)d_in[2];
    const float* WA0 = (const float*)d_in[3];
    const float* bA0 = (const float*)d_in[4];
    const float* WA1 = (const float*)d_in[5];
    const float* bA1 = (const float*)d_in[6];
    const float* WA2 = (const float*)d_in[7];
    const float* bA2 = (const float*)d_in[8];
    const float* Wm0 = (const float*)d_in[9];
    const float* bm0 = (const float*)d_in[10];
    const float* Wm1 = (const float*)d_in[11];
    const float* bm1 = (const float*)d_in[12];
    const float* wA  = (const float*)d_in[13];
    const float* wf  = (const float*)d_in[14];
    float* out = (float*)d_out;

    if (ws_size >= (size_t)NN * NN * 2) {
        __fp16* A16 = (__fp16*)d_ws;
        conv_kernel<<<2048, 256, 0, stream>>>(A, A16);
        odef_f16<<<NN / 4, 256, 0, stream>>>(A16, x, WA0, bA0, WA1, bA1,
                                             WA2, bA2, Wm0, bm0, Wm1, bm1,
                                             wA, wf, out);
    } else {
        odef_f32<<<NN / 4, 256, 0, stream>>>(x, A, WA0, bA0, WA1, bA1,
                                             WA2, bA2, Wm0, bm0, Wm1, bm1,
                                             wA, wf, out);
    }
}

// Round 10
// 145.323 us; speedup vs baseline: 1.1318x; 1.1318x over previous
//
#include <hip/hip_runtime.h>
#include <hip/hip_bf16.h>

// ODEFunc: out[i] = x_N(x_i) + sum_j A[i,j] * ( edgeMLP(x_i, x_j) + wA0*x_i + wA1*x_j )
//
// R22 = R20 supply pipeline + f32 epilogue (VALU-pipe-composition test):
//   R21 (decisive): bytes AND requests halved (f16 A, FETCH 33->16.7MB) ->
//   main kernel EXACTLY 43.2us = R20. Memory-supply family fully falsified
//   (bytes, requests, depth, occupancy, addresses all invariant). Conv
//   overhead reverted.
//   Surviving theory: packed-f16 VALU (pk_fma/pk_max/fdot2/cvt) occupies the
//   pipe ~4cyc/wave64 (2x f32 rate). Closes the VALUBusy arithmetic (static
//   104 ops/body -> 53% only if f16 ops are 2x) AND explains R12->R13 "null":
//   packed epilogue cut instructions, not pipe cycles.
//   * A/B this round: bias restored as MFMA C-operand (cbias, R18-proven) and
//     epilogue in PURE F32: 8 fmaxf + 8 fmaf (two 4-deep chains) directly on
//     D regs. No cvt, no pk_add, no fdot2. Under 4cyc-theory: -16% VALU
//     cycles; under 2cyc-theory: +10%. Either result resolves it.
//   * Supply = R20 verbatim: per-lane asm global_load_dwordx4, 32 SSA slots,
//     depth-8 counted vmcnt, sched_barrier after every wait, vmcnt(0)
//     baseline drain. 1 wave = 1 row, grid 1024, (256,4).
//   * f32 epilogue also improves absmax (R12-style, was 9.8e-4).
//
// MFMA layout (32x32x16, validated R2-R11):
//   A[m][k]: m = lane&31, k = (lane>>5)*8 + e
//   B[k][n]: n = lane&31, k = (lane>>5)*8 + e
//   D[m][n]: n = lane&31, m = (reg&3) + 8*(reg>>2) + 4*(lane>>5)
// Only m<16 carries WA1; D regs 8..15 ignored. C = cbias (bA1 in regs 0..7).
// In-lane epilogue: A_ij distributes into the WA2 dot; skip term in half 0 only.

#define NN 4096

typedef __fp16 half8  __attribute__((ext_vector_type(8)));
typedef __fp16 half2v __attribute__((ext_vector_type(2)));
typedef __attribute__((ext_vector_type(4)))  float f32x4;
typedef __attribute__((ext_vector_type(16))) float f32x16;

__device__ __forceinline__ half2v cvt2(float lo, float hi) {
    return __builtin_amdgcn_cvt_pkrtz(lo, hi);
}

__global__ __launch_bounds__(256, 4) void odef_kernel(
    const float* __restrict__ x,  const float* __restrict__ A,
    const float* __restrict__ WA0, const float* __restrict__ bA0,
    const float* __restrict__ WA1, const float* __restrict__ bA1,
    const float* __restrict__ WA2, const float* __restrict__ bA2,
    const float* __restrict__ Wm0, const float* __restrict__ bm0,
    const float* __restrict__ Wm1, const float* __restrict__ bm1,
    const float* __restrict__ wA,  const float* __restrict__ wf,
    float* __restrict__ out)
{
    __shared__ float xs[NN];         // full x vector, 16KB

    const int tid  = threadIdx.x;
    const int wave = tid >> 6;
    const int lane = tid & 63;
    const int n    = lane & 31;      // MFMA col (B n / D n / A m)
    const int half = lane >> 5;      // k-half (A/B), row-half (D)
    const int row  = blockIdx.x * 4 + wave;   // 1 full row per wave

    // ---- cooperative x -> LDS (1024 float4, 4 per thread)
    {
        const f32x4* xsrc = (const f32x4*)x;
        f32x4* xdst = (f32x4*)xs;
        #pragma unroll
        for (int i = 0; i < 4; ++i)
            xdst[tid + 256 * i] = xsrc[tid + 256 * i];
    }
    const float xi = x[row];

    // ---- A-fragment: WA1[m][k] in f16; m = n (<16), k = half*8 + e
    union { half2v h2[4]; half8 h8; } au;
    #pragma unroll
    for (int p = 0; p < 4; ++p) {
        float lo = 0.f, hi = 0.f;
        if (n < 16) {
            int k = half * 8 + p * 2;
            lo = WA1[n * 16 + k];
            hi = WA1[n * 16 + k + 1];
        }
        au.h2[p] = cvt2(lo, hi);
    }

    // ---- h0 constants, packed f16: u_k(i) = WA0[k,0]*xi + bA0[k]; w1_k = WA0[k,1]
    half2v u2h[4], w2h[4];
    #pragma unroll
    for (int p = 0; p < 4; ++p) {
        int k0 = half * 8 + p * 2;
        u2h[p] = cvt2(fmaf(WA0[2 * k0],     xi, bA0[k0]),
                      fmaf(WA0[2 * k0 + 2], xi, bA0[k0 + 1]));
        w2h[p] = cvt2(WA0[2 * k0 + 1], WA0[2 * k0 + 3]);
    }

    // ---- layer-2 weights (f32) + bias-as-C (rows (r&3)+8*(r>>2)+4*half, r<8)
    float wa2s[8];
    f32x16 cbias;
    #pragma unroll
    for (int r = 0; r < 16; ++r) cbias[r] = 0.f;
    #pragma unroll
    for (int r = 0; r < 8; ++r) {
        int m = (r & 3) + 8 * (r >> 2) + 4 * half;
        wa2s[r]  = WA2[m];
        cbias[r] = bA1[m];
    }

    // skip term: only half 0 adds it (each j is held by both halves)
    const float wA1h = half ? 0.f : wA[1];
    const float c0h  = half ? 0.f : (bA2[0] + wA[0] * xi);
    const half2v z2 = { (__fp16)0.f, (__fp16)0.f };

    float acc0 = 0.f, acc1 = 0.f;

    // one 128-j group: 4 MFMA sub-groups, 2-deep MFMA pipeline (proven R10+).
    // Epilogue in PURE F32: relu + WA2-dot directly on D regs, 2 chains.
    auto body = [&](const f32x4 xv, const f32x4 av) {
        #pragma unroll
        for (int q = 0; q < 4; q += 2) {
            half2v xg0 = cvt2(xv[q], xv[q]);
            union { half2v h2[4]; half8 h8; } b0;
            #pragma unroll
            for (int p = 0; p < 4; ++p)
                b0.h2[p] = __builtin_elementwise_max(w2h[p] * xg0 + u2h[p], z2);
            f32x16 d0 = __builtin_amdgcn_mfma_f32_32x32x16_f16(au.h8, b0.h8, cbias, 0, 0, 0);

            half2v xg1 = cvt2(xv[q + 1], xv[q + 1]);
            union { half2v h2[4]; half8 h8; } b1;
            #pragma unroll
            for (int p = 0; p < 4; ++p)
                b1.h2[p] = __builtin_elementwise_max(w2h[p] * xg1 + u2h[p], z2);
            f32x16 d1 = __builtin_amdgcn_mfma_f32_32x32x16_f16(au.h8, b1.h8, cbias, 0, 0, 0);

            // epilogue q: f32, two independent 4-deep fmaf chains
            {
                float pa = fmaf(wA1h, xv[q], c0h);
                float pb = 0.f;
                #pragma unroll
                for (int r = 0; r < 4; ++r) {
                    pa = fmaf(wa2s[2 * r],     fmaxf(d0[2 * r],     0.f), pa);
                    pb = fmaf(wa2s[2 * r + 1], fmaxf(d0[2 * r + 1], 0.f), pb);
                }
                acc0 = fmaf(av[q], pa + pb, acc0);
            }
            // epilogue q+1
            {
                float pa = fmaf(wA1h, xv[q + 1], c0h);
                float pb = 0.f;
                #pragma unroll
                for (int r = 0; r < 4; ++r) {
                    pa = fmaf(wa2s[2 * r],     fmaxf(d1[2 * r],     0.f), pa);
                    pb = fmaf(wa2s[2 * r + 1], fmaxf(d1[2 * r + 1], 0.f), pb);
                }
                acc1 = fmaf(av[q + 1], pa + pb, acc1);
            }
        }
    };

    __syncthreads();                 // xs ready

    // step t (0..31): lane covers float4 index n + 32t -> floats 4n + 128t.
    const float* ap = A + (size_t)row * NN + 4 * n;
    const f32x4* xls = (const f32x4*)xs;

    // asm load: invisible to compiler's waitcnt pass; paced ONLY by our waits.
#define LOADA(dst, p) \
    asm volatile("global_load_dwordx4 %0, %1, off" : "=v"(dst) : "v"(p))
#define WAITV(N) do {                                              \
    asm volatile("s_waitcnt vmcnt(" #N ")" ::: "memory");          \
    __builtin_amdgcn_sched_barrier(0); } while (0)

    // baseline: drain ALL prior vmem (constant-setup loads) -> counter exact
    __builtin_amdgcn_sched_barrier(0);
    asm volatile("s_waitcnt vmcnt(0)" ::: "memory");
    __builtin_amdgcn_sched_barrier(0);

    // 32 single-assignment slots: each written by ONE asm load, read by ONE
    // body, <=8 live at any point -> no phis, no compiler copies (R19's bug).
    f32x4 L0,  L1,  L2,  L3,  L4,  L5,  L6,  L7,
          L8,  L9,  L10, L11, L12, L13, L14, L15,
          L16, L17, L18, L19, L20, L21, L22, L23,
          L24, L25, L26, L27, L28, L29, L30, L31;

    LOADA(L0, ap + 128 * 0);  LOADA(L1, ap + 128 * 1);
    LOADA(L2, ap + 128 * 2);  LOADA(L3, ap + 128 * 3);
    LOADA(L4, ap + 128 * 4);  LOADA(L5, ap + 128 * 5);
    LOADA(L6, ap + 128 * 6);  LOADA(L7, ap + 128 * 7);

    // steps 0..23: wait-for-oldest = vmcnt(7), consume Lt, issue L(t+8)
#define STEPM(T, CUR, NXT) {                                       \
        f32x4 xv = xls[n + 32 * (T)];                              \
        WAITV(7);                                                  \
        body(xv, CUR);                                             \
        LOADA(NXT, ap + 128 * ((T) + 8)); }

    STEPM(0,  L0,  L8)   STEPM(1,  L1,  L9)   STEPM(2,  L2,  L10)
    STEPM(3,  L3,  L11)  STEPM(4,  L4,  L12)  STEPM(5,  L5,  L13)
    STEPM(6,  L6,  L14)  STEPM(7,  L7,  L15)  STEPM(8,  L8,  L16)
    STEPM(9,  L9,  L17)  STEPM(10, L10, L18)  STEPM(11, L11, L19)
    STEPM(12, L12, L20)  STEPM(13, L13, L21)  STEPM(14, L14, L22)
    STEPM(15, L15, L23)  STEPM(16, L16, L24)  STEPM(17, L17, L25)
    STEPM(18, L18, L26)  STEPM(19, L19, L27)  STEPM(20, L20, L28)
    STEPM(21, L21, L29)  STEPM(22, L22, L30)  STEPM(23, L23, L31)

    // tail: steps 24..31, descending counts, no new issues
#define STEPT(T, WN, CUR) {                                        \
        f32x4 xv = xls[n + 32 * (T)];                              \
        WAITV(WN);                                                 \
        body(xv, CUR); }

    STEPT(24, 7, L24) STEPT(25, 6, L25) STEPT(26, 5, L26) STEPT(27, 4, L27)
    STEPT(28, 3, L28) STEPT(29, 2, L29) STEPT(30, 1, L30) STEPT(31, 0, L31)

#undef STEPM
#undef STEPT
#undef LOADA
#undef WAITV

    // ---- full-wave reduce; each wave owns its row
    float acc = acc0 + acc1;
    #pragma unroll
    for (int off = 32; off > 0; off >>= 1)
        acc += __shfl_xor(acc, off);

    if (lane == 0) {
        // node MLP (fp32 exact): x_N = relu(x*Wm0+bm0)@Wm1 + bm1 + wf*x
        float xn = fmaf(wf[0], xi, bm1[0]);
        #pragma unroll
        for (int h = 0; h < 16; ++h)
            xn = fmaf(Wm1[h], fmaxf(fmaf(Wm0[h], xi, bm0[h]), 0.f), xn);
        out[row] = xn + acc;
    }
}

extern "C" void kernel_launch(void* const* d_in, const int* in_sizes, int n_in,
                              void* d_out, int out_size, void* d_ws, size_t ws_size,
                              hipStream_t stream) {
    const float* x   = (const float*)d_in[1];
    const float* A   = (const float*)d_in[2];
    const float* WA0 = (const float*)d_in[3];
    const float* bA0 = (const float*)d_in[4];
    const float* WA1 = (const float*)d_in[5];
    const float* bA1 = (const float*)d_in[6];
    const float* WA2 = (const float*)d_in[7];
    const float* bA2 = (const float*)d_in[8];
    const float* Wm0 = (const float*)d_in[9];
    const float* bm0 = (const float*)d_in[10];
    const float* Wm1 = (const float*)d_in[11];
    const float* bm1 = (const float*)d_in[12];
    const float* wA  = (const float*)d_in[13];
    const float* wf  = (const float*)d_in[14];
    float* out = (float*)d_out;

    odef_kernel<<<NN / 4, 256, 0, stream>>>(x, A, WA0, bA0, WA1, bA1, WA2, bA2,
                                            Wm0, bm0, Wm1, bm1, wA, wf, out);
}

// Round 11
// 140.196 us; speedup vs baseline: 1.1731x; 1.0366x over previous
//
#include <hip/hip_runtime.h>
#include <hip/hip_bf16.h>

// ODEFunc: out[i] = x_N(x_i) + sum_j A[i,j] * ( edgeMLP(x_i, x_j) + wA0*x_i + wA1*x_j )
//
// R23 = epilogue-as-MFMA (VALU-pipe offload; first positive-slope signal):
//   R22 A/B: +VALU ops -> +VALUBusy (53->67) AND +time (+5%). VALU slope is
//   real; memory family fully falsified (R14/15/17/18/20/21 ledger). Model:
//   wall = per-step VALU pipe cycles (at sustained clocks < 2.4GHz, closing
//   the VALUBusy-vs-static-count gap); MFMA pipe 86% idle.
//   * wa2^T·relu(h2+bA1) IS a 1x16 matvec -> second mfma_32x32x16:
//     A2 = wa2 in row 0 (lanes with lane&31==0), B2 = relu'd h2 fragments.
//     MFMA1's D-reg order (rows (r&3)+8*(r>>2)+4h) is a valid B-fragment
//     k-order under row-permutation pi of WA1 -- wa2s[r]/cbias[r] indexing
//     already implements pi. out_j lands in D2 reg 0, half 0, lane n=col.
//   * bias bA1 via MFMA1 C-operand (cbias, R22-proven numerics 9.8e-4).
//   * per-group epilogue: 18 VALU -> 11 VALU + 1 MFMA (4 cvt2 + 4 pk_max +
//     skip-fmaf + add + acc-fmaf); body VALU pipe cycles -30%.
//   * half-1 lanes' d2[0] is a foreign row -> av masked to 0 there (4
//     cndmask/step); their reduce contribution is exactly 0.
//   * Supply = R20 verbatim (proven): per-lane asm global_load_dwordx4,
//     32 SSA slots, depth-8 counted vmcnt, sched_barrier per wait, vmcnt(0)
//     baseline. 1 wave = 1 row, grid 1024, (256,4), xs in LDS.
//
// MFMA layout (32x32x16, validated R2-R11):
//   A[m][k]: m = lane&31, k = (lane>>5)*8 + e
//   B[k][n]: n = lane&31, k = (lane>>5)*8 + e
//   D[m][n]: n = lane&31, m = (reg&3) + 8*(reg>>2) + 4*(lane>>5)

#define NN 4096

typedef __fp16 half8  __attribute__((ext_vector_type(8)));
typedef __fp16 half2v __attribute__((ext_vector_type(2)));
typedef __attribute__((ext_vector_type(4)))  float f32x4;
typedef __attribute__((ext_vector_type(16))) float f32x16;

__device__ __forceinline__ half2v cvt2(float lo, float hi) {
    return __builtin_amdgcn_cvt_pkrtz(lo, hi);
}

__global__ __launch_bounds__(256, 4) void odef_kernel(
    const float* __restrict__ x,  const float* __restrict__ A,
    const float* __restrict__ WA0, const float* __restrict__ bA0,
    const float* __restrict__ WA1, const float* __restrict__ bA1,
    const float* __restrict__ WA2, const float* __restrict__ bA2,
    const float* __restrict__ Wm0, const float* __restrict__ bm0,
    const float* __restrict__ Wm1, const float* __restrict__ bm1,
    const float* __restrict__ wA,  const float* __restrict__ wf,
    float* __restrict__ out)
{
    __shared__ float xs[NN];         // full x vector, 16KB

    const int tid  = threadIdx.x;
    const int wave = tid >> 6;
    const int lane = tid & 63;
    const int n    = lane & 31;      // MFMA col (B n / D n / A m)
    const int half = lane >> 5;      // k-half (A/B), row-half (D)
    const int row  = blockIdx.x * 4 + wave;   // 1 full row per wave

    // ---- cooperative x -> LDS (1024 float4, 4 per thread)
    {
        const f32x4* xsrc = (const f32x4*)x;
        f32x4* xdst = (f32x4*)xs;
        #pragma unroll
        for (int i = 0; i < 4; ++i)
            xdst[tid + 256 * i] = xsrc[tid + 256 * i];
    }
    const float xi = x[row];

    // ---- MFMA1 A-fragment: WA1[m][k] f16; m = n (<16), k = half*8 + e
    union { half2v h2[4]; half8 h8; } au;
    #pragma unroll
    for (int p = 0; p < 4; ++p) {
        float lo = 0.f, hi = 0.f;
        if (n < 16) {
            int k = half * 8 + p * 2;
            lo = WA1[n * 16 + k];
            hi = WA1[n * 16 + k + 1];
        }
        au.h2[p] = cvt2(lo, hi);
    }

    // ---- h0 constants, packed f16: u_k(i) = WA0[k,0]*xi + bA0[k]; w1_k
    half2v u2h[4], w2h[4];
    #pragma unroll
    for (int p = 0; p < 4; ++p) {
        int k0 = half * 8 + p * 2;
        u2h[p] = cvt2(fmaf(WA0[2 * k0],     xi, bA0[k0]),
                      fmaf(WA0[2 * k0 + 2], xi, bA0[k0 + 1]));
        w2h[p] = cvt2(WA0[2 * k0 + 1], WA0[2 * k0 + 3]);
    }

    // ---- bias-as-C for MFMA1 + MFMA2 A-fragment (wa2 in output-row 0).
    //      D-reg r of half h holds h2 row m(r,h)=(r&3)+8*(r>>2)+4h; as a
    //      B-fragment it supplies k=8h+r, so wa2'[8h+r]=WA2[m(r,h)] = the
    //      same indexing; lanes with n==0 carry A2 row 0, others zero.
    f32x16 cbias;
    #pragma unroll
    for (int r = 0; r < 16; ++r) cbias[r] = 0.f;
    union { half2v h2[4]; half8 h8; } au2;
    #pragma unroll
    for (int p = 0; p < 4; ++p) {
        int m0 = (2 * p & 3) + 8 * (2 * p >> 2) + 4 * half;
        int m1 = ((2 * p + 1) & 3) + 8 * ((2 * p + 1) >> 2) + 4 * half;
        cbias[2 * p]     = bA1[m0];
        cbias[2 * p + 1] = bA1[m1];
        au2.h2[p] = cvt2(n == 0 ? WA2[m0] : 0.f, n == 0 ? WA2[m1] : 0.f);
    }

    // skip term: only half 0 (half 1's d2[0] is a foreign row; av masked)
    const float wA1h = half ? 0.f : wA[1];
    const float c0h  = half ? 0.f : (bA2[0] + wA[0] * xi);
    const half2v z2 = { (__fp16)0.f, (__fp16)0.f };
    const f32x16 zc = {};

    float acc0 = 0.f, acc1 = 0.f;

    // one 128-j group: 4 MFMA1 + 4 MFMA2; 2-deep MFMA1 stagger (proven R10+)
    auto body = [&](const f32x4 xv, const f32x4 avm) {
        #pragma unroll
        for (int q = 0; q < 4; q += 2) {
            half2v xg0 = cvt2(xv[q], xv[q]);
            union { half2v h2[4]; half8 h8; } b0;
            #pragma unroll
            for (int p = 0; p < 4; ++p)
                b0.h2[p] = __builtin_elementwise_max(w2h[p] * xg0 + u2h[p], z2);
            f32x16 d0 = __builtin_amdgcn_mfma_f32_32x32x16_f16(au.h8, b0.h8, cbias, 0, 0, 0);

            half2v xg1 = cvt2(xv[q + 1], xv[q + 1]);
            union { half2v h2[4]; half8 h8; } b1;
            #pragma unroll
            for (int p = 0; p < 4; ++p)
                b1.h2[p] = __builtin_elementwise_max(w2h[p] * xg1 + u2h[p], z2);
            f32x16 d1 = __builtin_amdgcn_mfma_f32_32x32x16_f16(au.h8, b1.h8, cbias, 0, 0, 0);

            // epilogue q: relu+pack h2 (bias already in D), then MFMA2
            {
                union { half2v h2[4]; half8 h8; } t;
                #pragma unroll
                for (int p = 0; p < 4; ++p)
                    t.h2[p] = __builtin_elementwise_max(
                        cvt2(d0[2 * p], d0[2 * p + 1]), z2);
                f32x16 d2 = __builtin_amdgcn_mfma_f32_32x32x16_f16(au2.h8, t.h8, zc, 0, 0, 0);
                float sk = fmaf(wA1h, xv[q], c0h);
                acc0 = fmaf(avm[q], d2[0] + sk, acc0);
            }
            // epilogue q+1
            {
                union { half2v h2[4]; half8 h8; } t;
                #pragma unroll
                for (int p = 0; p < 4; ++p)
                    t.h2[p] = __builtin_elementwise_max(
                        cvt2(d1[2 * p], d1[2 * p + 1]), z2);
                f32x16 d2 = __builtin_amdgcn_mfma_f32_32x32x16_f16(au2.h8, t.h8, zc, 0, 0, 0);
                float sk = fmaf(wA1h, xv[q + 1], c0h);
                acc1 = fmaf(avm[q + 1], d2[0] + sk, acc1);
            }
        }
    };

    __syncthreads();                 // xs ready

    // step t (0..31): lane covers float4 index n + 32t -> floats 4n + 128t.
    const float* ap = A + (size_t)row * NN + 4 * n;
    const f32x4* xls = (const f32x4*)xs;
    const float hmask = half ? 0.f : 1.f;   // av mask: half-1 contributes 0

    // asm load: invisible to compiler's waitcnt pass; paced ONLY by our waits.
#define LOADA(dst, p) \
    asm volatile("global_load_dwordx4 %0, %1, off" : "=v"(dst) : "v"(p))
#define WAITV(N) do {                                              \
    asm volatile("s_waitcnt vmcnt(" #N ")" ::: "memory");          \
    __builtin_amdgcn_sched_barrier(0); } while (0)

    // baseline: drain ALL prior vmem (constant-setup loads) -> counter exact
    __builtin_amdgcn_sched_barrier(0);
    asm volatile("s_waitcnt vmcnt(0)" ::: "memory");
    __builtin_amdgcn_sched_barrier(0);

    // 32 single-assignment slots: each written by ONE asm load, read by ONE
    // body, <=8 live at any point -> no phis, no compiler copies (R19's bug).
    f32x4 L0,  L1,  L2,  L3,  L4,  L5,  L6,  L7,
          L8,  L9,  L10, L11, L12, L13, L14, L15,
          L16, L17, L18, L19, L20, L21, L22, L23,
          L24, L25, L26, L27, L28, L29, L30, L31;

    LOADA(L0, ap + 128 * 0);  LOADA(L1, ap + 128 * 1);
    LOADA(L2, ap + 128 * 2);  LOADA(L3, ap + 128 * 3);
    LOADA(L4, ap + 128 * 4);  LOADA(L5, ap + 128 * 5);
    LOADA(L6, ap + 128 * 6);  LOADA(L7, ap + 128 * 7);

    // steps 0..23: wait-for-oldest = vmcnt(7), consume Lt, issue L(t+8)
#define STEPM(T, CUR, NXT) {                                       \
        f32x4 xv = xls[n + 32 * (T)];                              \
        WAITV(7);                                                  \
        f32x4 avm = CUR * hmask;                                   \
        body(xv, avm);                                             \
        LOADA(NXT, ap + 128 * ((T) + 8)); }

    STEPM(0,  L0,  L8)   STEPM(1,  L1,  L9)   STEPM(2,  L2,  L10)
    STEPM(3,  L3,  L11)  STEPM(4,  L4,  L12)  STEPM(5,  L5,  L13)
    STEPM(6,  L6,  L14)  STEPM(7,  L7,  L15)  STEPM(8,  L8,  L16)
    STEPM(9,  L9,  L17)  STEPM(10, L10, L18)  STEPM(11, L11, L19)
    STEPM(12, L12, L20)  STEPM(13, L13, L21)  STEPM(14, L14, L22)
    STEPM(15, L15, L23)  STEPM(16, L16, L24)  STEPM(17, L17, L25)
    STEPM(18, L18, L26)  STEPM(19, L19, L27)  STEPM(20, L20, L28)
    STEPM(21, L21, L29)  STEPM(22, L22, L30)  STEPM(23, L23, L31)

    // tail: steps 24..31, descending counts, no new issues
#define STEPT(T, WN, CUR) {                                        \
        f32x4 xv = xls[n + 32 * (T)];                              \
        WAITV(WN);                                                 \
        f32x4 avm = CUR * hmask;                                   \
        body(xv, avm); }

    STEPT(24, 7, L24) STEPT(25, 6, L25) STEPT(26, 5, L26) STEPT(27, 4, L27)
    STEPT(28, 3, L28) STEPT(29, 2, L29) STEPT(30, 1, L30) STEPT(31, 0, L31)

#undef STEPM
#undef STEPT
#undef LOADA
#undef WAITV

    // ---- full-wave reduce; each wave owns its row
    float acc = acc0 + acc1;
    #pragma unroll
    for (int off = 32; off > 0; off >>= 1)
        acc += __shfl_xor(acc, off);

    if (lane == 0) {
        // node MLP (fp32 exact): x_N = relu(x*Wm0+bm0)@Wm1 + bm1 + wf*x
        float xn = fmaf(wf[0], xi, bm1[0]);
        #pragma unroll
        for (int h = 0; h < 16; ++h)
            xn = fmaf(Wm1[h], fmaxf(fmaf(Wm0[h], xi, bm0[h]), 0.f), xn);
        out[row] = xn + acc;
    }
}

extern "C" void kernel_launch(void* const* d_in, const int* in_sizes, int n_in,
                              void* d_out, int out_size, void* d_ws, size_t ws_size,
                              hipStream_t stream) {
    const float* x   = (const float*)d_in[1];
    const float* A   = (const float*)d_in[2];
    const float* WA0 = (const float*)d_in[3];
    const float* bA0 = (const float*)d_in[4];
    const float* WA1 = (const float*)d_in[5];
    const float* bA1 = (const float*)d_in[6];
    const float* WA2 = (const float*)d_in[7];
    const float* bA2 = (const float*)d_in[8];
    const float* Wm0 = (const float*)d_in[9];
    const float* bm0 = (const float*)d_in[10];
    const float* Wm1 = (const float*)d_in[11];
    const float* bm1 = (const float*)d_in[12];
    const float* wA  = (const float*)d_in[13];
    const float* wf  = (const float*)d_in[14];
    float* out = (float*)d_out;

    odef_kernel<<<NN / 4, 256, 0, stream>>>(x, A, WA0, bA0, WA1, bA1, WA2, bA2,
                                            Wm0, bm0, Wm1, bm1, wA, wf, out);
}